// Round 3
// baseline (526.153 us; speedup 1.0000x reference)
//
#include <hip/hip_runtime.h>
#include <hip/hip_bf16.h>
#include <cstdint>
#include <cstddef>

#define H 256
#define L 128
#define B 512
#define LEVELS 7
#define BH (B * H)            // 131072
#define NODE_STRIDE (2 * BH)  // hi plane + lo plane, u16 elements

// d_out layout (flat f32 element offsets), return order:
// root[B,H], internal_states[255,B,H], internal_mask[255,B],
// leaves[L,B,H], leaves_aux[L,B,H], leaves_mask[L,B]
#define OFF_ROOT 0
#define OFF_INT (B * H)
#define OFF_IMASK (OFF_INT + 255 * BH)
#define OFF_LEAVES (OFF_IMASK + 255 * B)
#define OFF_LAUX (OFF_LEAVES + L * BH)
#define OFF_LMASK (OFF_LAUX + L * BH)

typedef unsigned short u16;
typedef __attribute__((ext_vector_type(8))) short short8;
typedef __attribute__((ext_vector_type(16))) float f32x16;

__device__ __forceinline__ int postorder_pos(int level, int j) {
    int start = 0;
    for (int k = level; k <= LEVELS; ++k) {
        if ((j >> (k - level)) & 1) start += (2 << k) - 1;
    }
    return start + (2 << level) - 2;
}

__device__ __forceinline__ float sigm(float x) { return 1.0f / (1.0f + __expf(-x)); }

__device__ __forceinline__ u16 f2bf(float x) {
    __hip_bfloat16 b = __float2bfloat16(x);
    u16 u;
    __builtin_memcpy(&u, &b, 2);
    return u;
}
__device__ __forceinline__ float bfc(u16 u) {
    union { unsigned int ui; float f; } c;
    c.ui = ((unsigned int)u) << 16;
    return c.f;
}

__device__ __forceinline__ void gload16(const void* g, const void* l) {
    __builtin_amdgcn_global_load_lds(
        (const __attribute__((address_space(1))) void*)g,
        (__attribute__((address_space(3))) void*)l, 16, 0, 0);
}

// ---------------- gather: leaves, aux, level-0 post-order h, leaf split ----
__global__ __launch_bounds__(256) void gather_kernel(
    const int* __restrict__ tok, const float* __restrict__ emb,
    const float* __restrict__ emb_aux, float* __restrict__ out,
    u16* __restrict__ spLeaf, int do_split) {
    int row = blockIdx.x * 4 + (threadIdx.x >> 6);
    int f4i = threadIdx.x & 63;
    int l = row >> 9, b = row & 511;
    int t = tok[row];
    float4 e = reinterpret_cast<const float4*>(emb + (size_t)t * H)[f4i];
    float4 ea = reinterpret_cast<const float4*>(emb_aux + (size_t)t * H)[f4i];
    reinterpret_cast<float4*>(out + OFF_LEAVES)[(size_t)row * 64 + f4i] = e;
    reinterpret_cast<float4*>(out + OFF_LAUX)[(size_t)row * 64 + f4i] = ea;
    int pp = postorder_pos(0, l);
    reinterpret_cast<float4*>(out + OFF_INT + (size_t)pp * BH + (size_t)b * H)[f4i] = e;
    if (do_split) {
        float xs[4] = {e.x, e.y, e.z, e.w};
        ushort4 hv, lv;
        u16 h0 = f2bf(xs[0]); hv.x = h0; lv.x = f2bf(xs[0] - bfc(h0));
        u16 h1 = f2bf(xs[1]); hv.y = h1; lv.y = f2bf(xs[1] - bfc(h1));
        u16 h2 = f2bf(xs[2]); hv.z = h2; lv.z = f2bf(xs[2] - bfc(h2));
        u16 h3 = f2bf(xs[3]); hv.w = h3; lv.w = f2bf(xs[3] - bfc(h3));
        u16* np = spLeaf + (size_t)l * NODE_STRIDE + (size_t)b * H + 4 * f4i;
        *reinterpret_cast<ushort4*>(np) = hv;
        *reinterpret_cast<ushort4*>(np + BH) = lv;
    }
}

// ---------------- W pre-pack (+ masks fused) ----------------
// Layout: [hcb=8][kb=16][cc=160][kk=32], cc = gate*32 + (hc-hcb*32).
__global__ __launch_bounds__(256) void wpack_kernel(const float* __restrict__ W,
                                                    u16* __restrict__ hi,
                                                    u16* __restrict__ lo,
                                                    float* __restrict__ out) {
    int e = blockIdx.x * 256 + threadIdx.x; // 0 .. 655359
    int kk = e & 31;
    int idx2 = e >> 5;
    int cc = idx2 % 160;
    int t = idx2 / 160;
    int kb = t & 15, hcb = t >> 4;
    int k = kb * 32 + kk;
    int col = (cc >> 5) * 256 + hcb * 32 + (cc & 31);
    float x = W[(size_t)k * 1280 + col];
    u16 h = f2bf(x);
    hi[e] = h;
    lo[e] = f2bf(x - bfc(h));
    if (e < 255 * B) out[OFF_IMASK + e] = 1.0f;
    if (e < L * B) out[OFF_LMASK + e] = 1.0f;
}

// ---------------- fused split-bf16 32x32x16 MFMA GEMM + LSTM gates ---------
// Block: 128 thr (2 waves), BM=128 rows x 32 hc (=160 gate cols), BK=32.
// Each wave owns 64 rows x all 160 cols: acc[2 Mfrag][5 Nfrag] f32x16.
template <bool PRESPLIT>
__global__ __launch_bounds__(128, 2) void lstm_level_kernel(
    const u16* __restrict__ Whi, const u16* __restrict__ Wlo,
    const float* __restrict__ bias, const float* __restrict__ c_prev,
    float* __restrict__ c_out, float* __restrict__ out, int level,
    const u16* __restrict__ spIn, u16* __restrict__ spOut) {
    __shared__ __align__(16) u16 Ahi[128][32];
    __shared__ __align__(16) u16 Alo[128][32];
    __shared__ __align__(16) u16 Wst[2][5120]; // [hi/lo][cc*32+kk]

    const int tid = threadIdx.x;
    const int lane = tid & 63;
    const int wm = tid >> 6; // 0..1
    const int l31 = lane & 31;
    const int lh = lane >> 5;
    const int p = blockIdx.x >> 2;
    const int b0 = (blockIdx.x & 3) * 128;
    const int hcb = blockIdx.y;
    const int hc0 = hcb * 32;

    // acc[mf][nf]: 32-row Mfrag (rows 64*wm+32*mf+...), nf = gate (32 cols)
    f32x16 acc[2][5];
#pragma unroll
    for (int nf = 0; nf < 5; ++nf) {
        float bv = bias[nf * H + hc0 + l31];
        f32x16 v;
#pragma unroll
        for (int r = 0; r < 16; ++r) v[r] = bv;
        acc[0][nf] = v;
        acc[1][nf] = v;
    }

    const float* hL = nullptr;
    const float* hR = nullptr;
    const u16* sL = nullptr;
    const u16* sR = nullptr;
    if constexpr (PRESPLIT) {
        sL = spIn + (size_t)(2 * p) * NODE_STRIDE;
        sR = sL + NODE_STRIDE;
    } else {
        hL = out + OFF_INT + (size_t)postorder_pos(level - 1, 2 * p) * BH;
        hR = out + OFF_INT + (size_t)postorder_pos(level - 1, 2 * p + 1) * BH;
    }

    for (int kb = 0; kb < 16; ++kb) {
        // --- W tile: linear async stage (pre-packed) ---
        const u16* gH = Whi + (size_t)(hcb * 16 + kb) * 5120;
        const u16* gL = Wlo + (size_t)(hcb * 16 + kb) * 5120;
#pragma unroll
        for (int i = 0; i < 5; ++i) {
            int c = 5 * wm + i; // 10 x 1KB chunks per plane
            gload16(gH + c * 512 + lane * 8, &Wst[0][c * 512]);
            gload16(gL + c * 512 + lane * 8, &Wst[1][c * 512]);
        }
        const int kc0 = (kb & 7) * 32;
        if constexpr (PRESPLIT) {
            // --- A tile: pure async stage from pre-split planes ---
            const u16* nb = (kb < 8) ? sL : sR;
#pragma unroll
            for (int i = 0; i < 4; ++i) {
                int c = 4 * wm + i; // 8 x 1KB chunks per plane
                int row = 16 * c + (lane >> 2);
                size_t go = (size_t)(b0 + row) * H + kc0 + 8 * (lane & 3);
                gload16(nb + go, (u16*)Ahi + c * 512);
                gload16(nb + BH + go, (u16*)Alo + c * 512);
            }
        } else {
            // --- fallback: read f32 h, split in-kernel ---
            const float* hsrc = (kb < 8) ? hL : hR;
#pragma unroll
            for (int it = 0; it < 4; ++it) {
                int q = tid + 128 * it;
                int rr = q >> 2, kg = q & 3;
                const float* src = hsrc + (size_t)(b0 + rr) * H + kc0 + kg * 8;
                float4 v0 = *reinterpret_cast<const float4*>(src);
                float4 v1 = *reinterpret_cast<const float4*>(src + 4);
                float xs[8] = {v0.x, v0.y, v0.z, v0.w, v1.x, v1.y, v1.z, v1.w};
                short8 hv, lv;
#pragma unroll
                for (int i2 = 0; i2 < 8; ++i2) {
                    u16 hu = f2bf(xs[i2]);
                    hv[i2] = (short)hu;
                    lv[i2] = (short)f2bf(xs[i2] - bfc(hu));
                }
                *reinterpret_cast<short8*>(&Ahi[rr][kg * 8]) = hv;
                *reinterpret_cast<short8*>(&Alo[rr][kg * 8]) = lv;
            }
        }
        __syncthreads();

        // --- MFMA: acc += Ahi*Whi + Alo*Whi + Ahi*Wlo (3-term split) ---
#pragma unroll
        for (int ks = 0; ks < 2; ++ks) {
            short8 ah[2], al[2];
#pragma unroll
            for (int mf = 0; mf < 2; ++mf) {
                ah[mf] = *reinterpret_cast<const short8*>(
                    &Ahi[64 * wm + 32 * mf + l31][16 * ks + 8 * lh]);
                al[mf] = *reinterpret_cast<const short8*>(
                    &Alo[64 * wm + 32 * mf + l31][16 * ks + 8 * lh]);
            }
#pragma unroll
            for (int nf = 0; nf < 5; ++nf) {
                const int wo = (32 * nf + l31) * 32 + 16 * ks + 8 * lh;
                short8 bh = *reinterpret_cast<const short8*>(&Wst[0][wo]);
                short8 bl = *reinterpret_cast<const short8*>(&Wst[1][wo]);
                acc[0][nf] = __builtin_amdgcn_mfma_f32_32x32x16_bf16(ah[0], bh, acc[0][nf], 0, 0, 0);
                acc[1][nf] = __builtin_amdgcn_mfma_f32_32x32x16_bf16(ah[1], bh, acc[1][nf], 0, 0, 0);
                acc[0][nf] = __builtin_amdgcn_mfma_f32_32x32x16_bf16(al[0], bh, acc[0][nf], 0, 0, 0);
                acc[1][nf] = __builtin_amdgcn_mfma_f32_32x32x16_bf16(al[1], bh, acc[1][nf], 0, 0, 0);
                acc[0][nf] = __builtin_amdgcn_mfma_f32_32x32x16_bf16(ah[0], bl, acc[0][nf], 0, 0, 0);
                acc[1][nf] = __builtin_amdgcn_mfma_f32_32x32x16_bf16(ah[1], bl, acc[1][nf], 0, 0, 0);
            }
        }
        __syncthreads();
    }

    // --- epilogue: gates -> c, h; write f32 outputs + split-bf16 scratch ---
    const int pout = postorder_pos(level, p);
    float* __restrict__ hout = out + OFF_INT + (size_t)pout * BH;
    const float* cLb = c_prev ? c_prev + (size_t)(2 * p) * BH : nullptr;
    const float* cRb = c_prev ? c_prev + (size_t)(2 * p + 1) * BH : nullptr;
    float* __restrict__ cob = c_out + (size_t)p * BH;
    u16* __restrict__ soH = spOut ? spOut + (size_t)p * NODE_STRIDE : nullptr;
    const int hc = hc0 + l31;

#pragma unroll
    for (int mf = 0; mf < 2; ++mf) {
#pragma unroll
        for (int r = 0; r < 16; ++r) {
            // verified 32x32 C layout: row=(r&3)+8*(r>>2)+4*lh, col=l31
            const int b = b0 + 64 * wm + 32 * mf + 4 * lh + (r & 3) + 8 * (r >> 2);
            float ig = acc[mf][0][r], f1 = acc[mf][1][r], f2 = acc[mf][2][r];
            float og = acc[mf][3][r], ug = acc[mf][4][r];
            float cl = 0.f, cr = 0.f;
            if (c_prev) {
                cl = cLb[(size_t)b * H + hc];
                cr = cRb[(size_t)b * H + hc];
            }
            float c = sigm(ig) * tanhf(ug) + sigm(f1) * cl + sigm(f2) * cr;
            float hval = sigm(og) * tanhf(c);
            cob[(size_t)b * H + hc] = c;
            hout[(size_t)b * H + hc] = hval;
            if (soH) {
                u16 hh = f2bf(hval);
                soH[(size_t)b * H + hc] = hh;
                soH[BH + (size_t)b * H + hc] = f2bf(hval - bfc(hh));
            }
            if (level == LEVELS) out[OFF_ROOT + (size_t)b * H + hc] = hval;
        }
    }
}

extern "C" void kernel_launch(void* const* d_in, const int* in_sizes, int n_in,
                              void* d_out, int out_size, void* d_ws,
                              size_t ws_size, hipStream_t stream) {
    const int* tok = (const int*)d_in[0];
    const float* emb = (const float*)d_in[1];
    const float* emb_aux = (const float*)d_in[2];
    const float* W = (const float*)d_in[3];
    const float* bias = (const float*)d_in[4];
    float* out = (float*)d_out;

    // ws: cbuf0 | cbuf1 (f32 c ping-pong) | Whi | Wlo | spEven(128) | spOdd(64)
    float* cbuf0 = (float*)d_ws;
    float* cbuf1 = cbuf0 + (size_t)64 * BH;
    u16* wphi = (u16*)(cbuf1 + (size_t)64 * BH);
    u16* wplo = wphi + (size_t)655360;
    u16* spEven = wplo + (size_t)655360;
    u16* spOdd = spEven + (size_t)128 * NODE_STRIDE;
    size_t need = (size_t)((char*)(spOdd + (size_t)64 * NODE_STRIDE) - (char*)d_ws);
    const bool presplit = ws_size >= need;

    hipLaunchKernelGGL(wpack_kernel, dim3(2560), dim3(256), 0, stream, W, wphi,
                       wplo, out);
    hipLaunchKernelGGL(gather_kernel, dim3(L * B / 4), dim3(256), 0, stream,
                       tok, emb, emb_aux, out, spEven, presplit ? 1 : 0);

    for (int level = 1; level <= LEVELS; ++level) {
        int n = L >> level;
        float* c_out = ((level - 1) & 1) ? cbuf1 : cbuf0;
        const float* c_prev =
            (level == 1) ? nullptr : ((level & 1) ? cbuf1 : cbuf0);
        const u16* spIn = (level & 1) ? spEven : spOdd;
        u16* spOutP =
            (level == LEVELS) ? nullptr : ((level & 1) ? spOdd : spEven);
        dim3 grid(4 * n, 8);
        if (presplit) {
            lstm_level_kernel<true><<<grid, dim3(128), 0, stream>>>(
                wphi, wplo, bias, c_prev, c_out, out, level, spIn, spOutP);
        } else {
            lstm_level_kernel<false><<<grid, dim3(128), 0, stream>>>(
                wphi, wplo, bias, c_prev, c_out, out, level, nullptr, nullptr);
        }
    }
}

// Round 4
// 385.961 us; speedup vs baseline: 1.3632x; 1.3632x over previous
//
#include <hip/hip_runtime.h>
#include <hip/hip_bf16.h>
#include <hip/hip_fp16.h>
#include <cstdint>
#include <cstddef>

#define H 256
#define L 128
#define B 512
#define LEVELS 7
#define BH (B * H) // 131072

// d_out layout (flat f32 element offsets), return order:
// root[B,H], internal_states[255,B,H], internal_mask[255,B],
// leaves[L,B,H], leaves_aux[L,B,H], leaves_mask[L,B]
#define OFF_ROOT 0
#define OFF_INT (B * H)
#define OFF_IMASK (OFF_INT + 255 * BH)
#define OFF_LEAVES (OFF_IMASK + 255 * B)
#define OFF_LAUX (OFF_LEAVES + L * BH)
#define OFF_LMASK (OFF_LAUX + L * BH)

typedef unsigned short u16;
typedef __attribute__((ext_vector_type(8))) _Float16 half8;
typedef __attribute__((ext_vector_type(16))) float f32x16;

// Fragment-major plane layout (fp16, per node, B x H):
// tile T = (b>>5)*16 + (hc>>4)  (1 KiB = 64 lanes x 16 B)
// lane  = (b&31) + 32*((hc>>3)&1),  elem = hc&7
// u16 offset = T*512 + lane*8 + elem
// -> matches verified 32x32x16 A-frag: row = lane&31, k-oct = lane>>5.

__device__ __forceinline__ int postorder_pos(int level, int j) {
    int start = 0;
    for (int k = level; k <= LEVELS; ++k) {
        if ((j >> (k - level)) & 1) start += (2 << k) - 1;
    }
    return start + (2 << level) - 2;
}

__device__ __forceinline__ float sigm(float x) { return 1.0f / (1.0f + __expf(-x)); }

__device__ __forceinline__ u16 f2h(float x) {
    _Float16 h = (_Float16)x;
    u16 u;
    __builtin_memcpy(&u, &h, 2);
    return u;
}

__device__ __forceinline__ void gload16(const void* g, const void* l) {
    __builtin_amdgcn_global_load_lds(
        (const __attribute__((address_space(1))) void*)g,
        (__attribute__((address_space(3))) void*)l, 16, 0, 0);
}

// ---------------- gather: leaves, aux, level-0 post-order h, leaf planes ----
__global__ __launch_bounds__(256) void gather_kernel(
    const int* __restrict__ tok, const float* __restrict__ emb,
    const float* __restrict__ emb_aux, float* __restrict__ out,
    u16* __restrict__ spLeaf, int do_split) {
    int row = blockIdx.x * 4 + (threadIdx.x >> 6);
    int f4i = threadIdx.x & 63;
    int l = row >> 9, b = row & 511;
    int t = tok[row];
    float4 e = reinterpret_cast<const float4*>(emb + (size_t)t * H)[f4i];
    float4 ea = reinterpret_cast<const float4*>(emb_aux + (size_t)t * H)[f4i];
    reinterpret_cast<float4*>(out + OFF_LEAVES)[(size_t)row * 64 + f4i] = e;
    reinterpret_cast<float4*>(out + OFF_LAUX)[(size_t)row * 64 + f4i] = ea;
    int pp = postorder_pos(0, l);
    reinterpret_cast<float4*>(out + OFF_INT + (size_t)pp * BH + (size_t)b * H)[f4i] = e;
    if (do_split) {
        // hc = 4*f4i + 0..3 -> same tile, same lane, elems elem0..elem0+3
        int ko = f4i >> 2;
        int lanep = (b & 31) + 32 * ((f4i >> 1) & 1);
        int elem0 = 4 * (f4i & 1);
        ushort4 hv;
        hv.x = f2h(e.x); hv.y = f2h(e.y); hv.z = f2h(e.z); hv.w = f2h(e.w);
        u16* np = spLeaf + (size_t)l * BH +
                  (size_t)(((b >> 5) * 16 + ko) * 512 + lanep * 8 + elem0);
        *reinterpret_cast<ushort4*>(np) = hv;
    }
}

// ---------------- W pre-pack into fragment-major fp16 tiles (+ masks) -------
// Pack layout: [hcb=8][kb=16][tile = gate*2 + ks][lane][8], 1 KiB tiles.
// lane = col_local + 32*oct; k = kb*32 + ks*16 + oct*8 + elem.
__global__ __launch_bounds__(256) void wpack_kernel(const float* __restrict__ W,
                                                    u16* __restrict__ wp,
                                                    float* __restrict__ out) {
    int q = blockIdx.x * 256 + threadIdx.x; // 0 .. 655359, coalesced read
    int k = q / 1280, col = q - k * 1280;
    int gate = col >> 8, hc = col & 255;
    int hcb = hc >> 5, cl = hc & 31;
    int kb = k >> 5, klr = k & 31;
    int ks = klr >> 4, oct = (klr >> 3) & 1, elem = klr & 7;
    size_t off = ((size_t)(hcb * 16 + kb) * 10 + gate * 2 + ks) * 512 +
                 (cl + 32 * oct) * 8 + elem;
    wp[off] = f2h(W[q]);
    if (q < 255 * B) out[OFF_IMASK + q] = 1.0f;
    if (q < L * B) out[OFF_LMASK + q] = 1.0f;
}

// ---------------- fused fp16 32x32x16 MFMA GEMM + LSTM gates ----------------
// Block: 128 thr (2 waves). Tile BM=128 rows x 32 hc (=160 gate cols), BK=32.
// Wave owns 64 rows (mf=2) x all 5 gates (nf=5): acc = 10 x f32x16.
// 2-phase double-buffered: stage kb+1 async, then ds_read+MFMA kb, 1 barrier.
template <bool PRESPLIT>
__global__ __launch_bounds__(128, 2) void lstm_level_kernel(
    const u16* __restrict__ wp, const float* __restrict__ bias,
    const float* __restrict__ c_prev, float* __restrict__ c_out,
    float* __restrict__ out, int level, const u16* __restrict__ spIn,
    u16* __restrict__ spOut) {
    __shared__ __align__(16) u16 Ald[2][8 * 512];   // 2 x 8 KiB
    __shared__ __align__(16) u16 Wld[2][10 * 512];  // 2 x 10 KiB

    const int tid = threadIdx.x;
    const int lane = tid & 63;
    const int wm = tid >> 6; // 0..1
    const int l31 = lane & 31;
    const int lh = lane >> 5;
    const int p = blockIdx.x >> 2;
    const int b0 = (blockIdx.x & 3) * 128;
    const int hcb = blockIdx.y;
    const int hc0 = hcb * 32;

    f32x16 acc[2][5];
#pragma unroll
    for (int nf = 0; nf < 5; ++nf) {
        float bv = bias[nf * H + hc0 + l31];
        f32x16 v;
#pragma unroll
        for (int r = 0; r < 16; ++r) v[r] = bv;
        acc[0][nf] = v;
        acc[1][nf] = v;
    }

    const u16* sL = nullptr;
    const u16* sR = nullptr;
    const float* hL = nullptr;
    const float* hR = nullptr;
    if constexpr (PRESPLIT) {
        sL = spIn + (size_t)(2 * p) * BH;
        sR = sL + BH;
    } else {
        hL = out + OFF_INT + (size_t)postorder_pos(level - 1, 2 * p) * BH;
        hR = out + OFF_INT + (size_t)postorder_pos(level - 1, 2 * p + 1) * BH;
    }

    // ---- stage kb into buffer buf ----
    auto stage = [&](int buf, int kb) {
        // W: 10 tiles, 5 per wave
        const u16* wsrc = wp + ((size_t)(hcb * 16 + kb) * 10) * 512;
#pragma unroll
        for (int i = 0; i < 5; ++i) {
            int t = 5 * wm + i;
            gload16(wsrc + t * 512 + lane * 8, &Wld[buf][t * 512]);
        }
        if constexpr (PRESPLIT) {
            const u16* plane = (kb < 8) ? sL : sR;
            const int Tbase = (b0 >> 5) * 16 + (kb & 7) * 2;
#pragma unroll
            for (int i = 0; i < 4; ++i) {
                int a = 4 * wm + i;             // 0..7
                int rg = a >> 1, kol = a & 1;
                gload16(plane + (size_t)(Tbase + rg * 16 + kol) * 512 + lane * 8,
                        &Ald[buf][a * 512]);
            }
        } else {
            const float* hsrc = (kb < 8) ? hL : hR;
            const int kc = (kb & 7) * 32;
#pragma unroll
            for (int i = 0; i < 4; ++i) {
                int oid = tid + 128 * i; // 0..511 octets
                int a = oid >> 6, lo = oid & 63;
                int rg = a >> 1, kol = a & 1;
                int bb = b0 + 32 * rg + (lo & 31);
                int hcc = kc + kol * 16 + (lo >> 5) * 8;
                const float* s = hsrc + (size_t)bb * H + hcc;
                float4 v0 = *reinterpret_cast<const float4*>(s);
                float4 v1 = *reinterpret_cast<const float4*>(s + 4);
                half8 hv;
                hv[0] = (_Float16)v0.x; hv[1] = (_Float16)v0.y;
                hv[2] = (_Float16)v0.z; hv[3] = (_Float16)v0.w;
                hv[4] = (_Float16)v1.x; hv[5] = (_Float16)v1.y;
                hv[6] = (_Float16)v1.z; hv[7] = (_Float16)v1.w;
                *reinterpret_cast<half8*>(&Ald[buf][a * 512 + lo * 8]) = hv;
            }
        }
    };

    stage(0, 0);
    __syncthreads(); // compiler drains vmcnt before s_barrier

    for (int kb = 0; kb < 16; ++kb) {
        const int buf = kb & 1;
        if (kb < 15) stage(buf ^ 1, kb + 1); // async loads overlap MFMA below
        const u16* Ab = Ald[buf];
        const u16* Wb = Wld[buf];
#pragma unroll
        for (int ks = 0; ks < 2; ++ks) {
            // A-frag tile index = rg*2 + ks, rg = 2*wm + mf
            half8 a0 = *reinterpret_cast<const half8*>(
                &Ab[((4 * wm + 0 + ks) * 512) + lane * 8]);
            half8 a1 = *reinterpret_cast<const half8*>(
                &Ab[((4 * wm + 2 + ks) * 512) + lane * 8]);
#pragma unroll
            for (int nf = 0; nf < 5; ++nf) {
                half8 bf = *reinterpret_cast<const half8*>(
                    &Wb[((nf * 2 + ks) * 512) + lane * 8]);
                acc[0][nf] = __builtin_amdgcn_mfma_f32_32x32x16_f16(
                    a0, bf, acc[0][nf], 0, 0, 0);
                acc[1][nf] = __builtin_amdgcn_mfma_f32_32x32x16_f16(
                    a1, bf, acc[1][nf], 0, 0, 0);
            }
        }
        __syncthreads();
    }

    // --- epilogue: gates -> c, h; f32 outputs + fp16 plane for next level ---
    const int pout = postorder_pos(level, p);
    float* __restrict__ hout = out + OFF_INT + (size_t)pout * BH;
    const float* cLb = c_prev ? c_prev + (size_t)(2 * p) * BH : nullptr;
    const float* cRb = c_prev ? c_prev + (size_t)(2 * p + 1) * BH : nullptr;
    float* __restrict__ cob = c_out + (size_t)p * BH;
    u16* __restrict__ soH = spOut ? spOut + (size_t)p * BH : nullptr;
    const int hc = hc0 + l31;
    const int kop = hcb * 2 + (l31 >> 4);
    const int lpp = 32 * ((l31 >> 3) & 1);
    const int elp = l31 & 7;

#pragma unroll
    for (int mf = 0; mf < 2; ++mf) {
#pragma unroll
        for (int r = 0; r < 16; ++r) {
            // verified 32x32 C layout: row = (r&3)+8*(r>>2)+4*lh, col = l31
            const int b = b0 + 64 * wm + 32 * mf + 4 * lh + (r & 3) + 8 * (r >> 2);
            float ig = acc[mf][0][r], f1 = acc[mf][1][r], f2 = acc[mf][2][r];
            float og = acc[mf][3][r], ug = acc[mf][4][r];
            float cl = 0.f, cr = 0.f;
            if (c_prev) {
                cl = cLb[(size_t)b * H + hc];
                cr = cRb[(size_t)b * H + hc];
            }
            float c = sigm(ig) * tanhf(ug) + sigm(f1) * cl + sigm(f2) * cr;
            float hval = sigm(og) * tanhf(c);
            cob[(size_t)b * H + hc] = c;
            hout[(size_t)b * H + hc] = hval;
            if (soH) {
                soH[(size_t)((b >> 5) * 16 + kop) * 512 +
                    (size_t)((b & 31) + lpp) * 8 + elp] = f2h(hval);
            }
            if (level == LEVELS) out[OFF_ROOT + (size_t)b * H + hc] = hval;
        }
    }
}

extern "C" void kernel_launch(void* const* d_in, const int* in_sizes, int n_in,
                              void* d_out, int out_size, void* d_ws,
                              size_t ws_size, hipStream_t stream) {
    const int* tok = (const int*)d_in[0];
    const float* emb = (const float*)d_in[1];
    const float* emb_aux = (const float*)d_in[2];
    const float* W = (const float*)d_in[3];
    const float* bias = (const float*)d_in[4];
    float* out = (float*)d_out;

    // ws: cbuf0 | cbuf1 (f32 c ping-pong, 32MB each) | wp (1.31MB fp16 pack)
    //     | spEven (128 planes fp16, 32MB) | spOdd (64 planes, 16MB)
    float* cbuf0 = (float*)d_ws;
    float* cbuf1 = cbuf0 + (size_t)64 * BH;
    u16* wp = (u16*)(cbuf1 + (size_t)64 * BH);
    u16* spEven = wp + (size_t)655360;
    u16* spOdd = spEven + (size_t)128 * BH;
    size_t need =
        (size_t)((char*)(spOdd + (size_t)64 * BH) - (char*)d_ws);
    const bool presplit = ws_size >= need;

    hipLaunchKernelGGL(wpack_kernel, dim3(2560), dim3(256), 0, stream, W, wp,
                       out);
    hipLaunchKernelGGL(gather_kernel, dim3(L * B / 4), dim3(256), 0, stream,
                       tok, emb, emb_aux, out, spEven, presplit ? 1 : 0);

    for (int level = 1; level <= LEVELS; ++level) {
        int n = L >> level;
        float* c_out = ((level - 1) & 1) ? cbuf1 : cbuf0;
        const float* c_prev =
            (level == 1) ? nullptr : ((level & 1) ? cbuf1 : cbuf0);
        const u16* spIn = (level & 1) ? spEven : spOdd;
        u16* spOutP =
            (level == LEVELS) ? nullptr : ((level & 1) ? spOdd : spEven);
        dim3 grid(4 * n, 8);
        if (presplit) {
            lstm_level_kernel<true><<<grid, dim3(128), 0, stream>>>(
                wp, bias, c_prev, c_out, out, level, spIn, spOutP);
        } else {
            lstm_level_kernel<false><<<grid, dim3(128), 0, stream>>>(
                wp, bias, c_prev, c_out, out, level, nullptr,
                (level == LEVELS) ? nullptr
                                  : ((level & 1) ? spOdd : spEven));
        }
    }
}